// Round 1
// baseline (412.227 us; speedup 1.0000x reference)
//
#include <hip/hip_runtime.h>
#include <cmath>
#include <cstdint>

// ---------------- static configuration ----------------
// B=32, T=4096, C=3, 128 scales, out 224x224, N_PSI=4096, pad=2047.
// slot = c*32 + b (96 real, padded to 128), padded signal length 8190.
// Composite kernel per (scale, class): class 0..6 = interior phase (w mod 7),
// class 7 = w==0 (left-clipped), class 8 = w==223 (right-clipped).
// H rows: [160 zero guard][<=3311 data, 4-aligned][>=503 zero guard], stride 3968.
//
// x layout: SLOT-INTERLEAVED xpQ[m][g*4+e] = xp[m][g + 32*e], g in [0,32), e in [0,4).
// Lane g loads one v4f = slots {g, g+32, g+64, g+96} at time m, and per-e combined
// outputs across lanes 0-31 are 32 contiguous OT words -> coalesced atomic batches.
//
// Round 12: r11 measured VALUBusy 48%, occupancy 33% (2.6 waves/SIMD), HBM 7%,
// 0 bank conflicts -> per-wave VALU duty ~18%: latency-bound on per-it xpQ loads
// (xpQ + streamed H thrash per-XCD L2 -> L3-class latency ~1000cy vs only 256
// VALU cycles/it of cover). Fix: (a) C_RW 8->16 doubles FLOP/byte (512 VALU
// cyc per 4KB x-load, halves L2 traffic); (b) 1-it software prefetch of the 4
// xv quads puts ~512 cyc between load issue and use.
// Guard re-derivation at RW=16: per-chunk start spread <=396 (chunk 0 worst:
// w=0 has kr=1 -> start 128 low), staged idx in [-236, 3866] -> stride 3968
// (back guard >= 503 covers prev-row underflow; fwd 3866 < 3968 stays in-row),
// plus 512-float zero pad before row 0. Union len <= ~3704 -> 8 pieces.

constexpr int C_TP     = 8190;
constexpr int C_XROWS  = 8192;   // time rows in xpQ
constexpr long long C_HSTRIDE = 3968;
constexpr int C_HGUARD = 160;
constexpr int C_HPAD   = 512;    // zeroed floats before Hbuf row 0
constexpr int C_NCLS   = 9;
constexpr int C_RW     = 16;     // w's per block (consecutive)
constexpr int C_NCH    = 14;     // 224 / C_RW
constexpr int C_NW     = 224;
constexpr int C_SIGP   = 128;    // padded slots
constexpr int C_M      = 512;    // m per piece
constexpr int C_NP     = 8;      // max pieces (covers union len <= 3704)
constexpr int C_SQ     = 32;     // staged quads per row per phase (8 KB total)

typedef float v2f __attribute__((ext_vector_type(2)));
typedef float v4f __attribute__((ext_vector_type(4)));

// Replicate numpy: scales = logspace(log10(2), log10(204), 128).astype(f32);
// K = ceil(16*s + 1); d = (4094-K)//2; a = s * (16/4095) in double.
__device__ __forceinline__ void scale_params(int i, float& s32, int& K, int& d, double& a) {
  const double l2   = log10(2.0);
  const double l204 = log10(204.0);
  double step = (l204 - l2) / 127.0;
  double e = (i == 127) ? l204 : ((double)i * step + l2);
  double sv = pow(10.0, e);
  s32 = (float)sv;
  double sp = (double)s32;
  K = (int)ceil(sp * 16.0 + 1.0);
  d = (4094 - K) >> 1;
  a = sp * (16.0 / 4095.0);
}

// ---------------- build composite kernels H (+fused OT zero & xpQ build) -------------
// grid (128, 10): cls<9 -> H row; cls==9 -> zero OT strip + build xpQ strip.
__global__ __launch_bounds__(256) void k_build_H(const float* __restrict__ int_psi,
                                                 const float* __restrict__ x,
                                                 float* __restrict__ Hbuf,
                                                 int* __restrict__ meta,
                                                 float* __restrict__ xpQ,
                                                 float* __restrict__ OT) {
  int i   = blockIdx.x;   // scale (or strip index for cls==9)
  int cls = blockIdx.y;   // class

  if (cls == 9) {
    // zero OT strip: 128 strips x 7168 float4
    float4* otz = (float4*)OT + (long long)i * 7168;
    float4 z4 = make_float4(0.f, 0.f, 0.f, 0.f);
    for (int q = threadIdx.x; q < 7168; q += 256) otz[q] = z4;
    // zero the pre-Hbuf pad (row-0 front-underflow guard)
    if (i == 0) {
      float* pad = Hbuf - C_HPAD;
      for (int q = threadIdx.x; q < C_HPAD; q += 256) pad[q] = 0.f;
    }
    // build xpQ strip: 128 strips x 8192 floats; slot-interleaved, reflect pad
    for (int q = threadIdx.x; q < 8192; q += 256) {
      int idx = i * 8192 + q;
      int r   = idx & 127;
      int p   = idx >> 7;
      int g   = r >> 2;       // b
      int e   = r & 3;        // c (e==3 -> pad)
      float val = 0.f;
      if (e < 3 && p < C_TP) {
        int t = p - 2047;
        if (t < 0) t = -t;                 // x[2047-p]
        else if (t > 4095) t = 8190 - t;   // x[10237-p]
        val = x[(g * 4096 + t) * 3 + e];
      }
      xpQ[idx] = val;
    }
    return;
  }

  float s32; int K, d; double a;
  scale_params(i, s32, K, d, a);

  int wr = (cls < 7) ? ((cls == 0) ? 7 : cls) : ((cls == 7) ? 0 : 223);
  double ks = 4096.0 / 224.0;
  double sf = ((double)wr + 0.5) * ks - 0.5;
  int t_lo = (int)floor(sf - ks) + 1;
  int t_hi = (int)ceil(sf + ks) - 1;
  if (t_lo < 0) t_lo = 0;
  if (t_hi > 4095) t_hi = 4095;
  int nt  = t_hi - t_lo + 1;   // <= 37
  int npv = nt + 1;            // conv-point weights

  int p_lo = t_lo + d;
  int Lh   = K + npv - 1;
  int kr   = (cls == 0) ? 1 : ((cls == 8) ? 31 : 0);
  int off0 = p_lo - 128 * kr;
  int shift = off0 & 3;
  int offA  = off0 - shift;
  int rowLen = (shift + Lh + 3) & ~3;

  __shared__ double Wt_sh[40];
  __shared__ float  v_shf[40];
  __shared__ float  kern_sh[3352];

  // zero only the guard regions (data region [g0,g1) fully overwritten below)
  float* rowFull = Hbuf + (long long)(i * C_NCLS + cls) * C_HSTRIDE;
  int g0 = C_HGUARD + shift;
  int g1 = g0 + Lh;
  for (int q = threadIdx.x; q < g0; q += 256) rowFull[q] = 0.f;
  for (int q = g1 + threadIdx.x; q < (int)C_HSTRIDE; q += 256) rowFull[q] = 0.f;

  if (threadIdx.x == 0) {
    double Z = 0.0;
    for (int t = 0; t < nt; ++t) {
      double wv = 1.0 - fabs(sf - (double)(t + t_lo)) / ks;
      if (wv < 0.0) wv = 0.0;
      Wt_sh[t] = wv; Z += wv;
    }
    for (int t = 0; t < nt; ++t) Wt_sh[t] = Wt_sh[t] / Z;
    double sq = sqrt((double)s32);
    // v[p_lo + q] = -sqrt(s) * (Wt[q-1] - Wt[q])   (built in double, used f32)
    for (int q = 0; q < 40; ++q) {
      double wm1 = (q >= 1 && q <= nt)  ? Wt_sh[q - 1] : 0.0;
      double w0  = (q < nt)             ? Wt_sh[q]     : 0.0;
      v_shf[q] = (float)(-sq * (wm1 - w0));
    }
  }

  // flipped gathered wavelet: kernW[tau] = int_psi[clip(floor((K-1-tau)/a))]
  float* kernp = kern_sh + 40;
  int fillN = K + 80;
  for (int q = threadIdx.x; q < fillN; q += 256) {
    int tau = q - 40;
    float kv = 0.f;
    if (tau >= 0 && tau < K) {
      int u = K - 1 - tau;
      int jj = (int)floor((double)u / a);
      jj = jj < 0 ? 0 : (jj > 4095 ? 4095 : jj);
      kv = int_psi[jj];
    }
    kern_sh[q] = kv;
  }
  __syncthreads();

  float* row = rowFull + C_HGUARD;
  for (int q = threadIdx.x; q < Lh; q += 256) {
    float acc = 0.f;
    for (int t = 0; t < npv; ++t) acc += v_shf[t] * kernp[q - t];
    row[shift + q] = acc;
  }
  if (threadIdx.x == 0) {
    meta[(i * C_NCLS + cls) * 2 + 0] = offA;
    meta[(i * C_NCLS + cls) * 2 + 1] = rowLen;
  }
}

// ---------------- main: OT[scale][w][slot] += sum_{m in piece} xp[m][slot]*H_w[m] ------
// grid (piece, chunk, scale'), scale' reversed so heavy scales dispatch first.
// ONE wave; iteration-granular half-wave m-split; lane owns slots {g,g+32,g+64,g+96}.
// 16 w's per block; 4 phases of <=16 its (Hs 8KB); 1-it x prefetch.
__global__ __launch_bounds__(64, 4) void k_cwt_main(const float* __restrict__ xpQ,
                                                    const float* __restrict__ Hbuf,
                                                    const int* __restrict__ meta,
                                                    float* __restrict__ OT) {
  int piece = blockIdx.x;           // 0..7
  int chunk = blockIdx.y;           // 0..13
  int i     = 127 - blockIdx.z;     // heavy scales first
  int lane  = threadIdx.x;          // 0..63
  int g     = lane & 31;
  int half  = lane >> 5;

  __shared__ v4f Hs[C_RW][C_SQ];    // 8 KB (per phase)

  v2f accL[C_RW], accH[C_RW];
  int U0 = 0x7fffffff, U1 = 0;
#pragma unroll
  for (int j = 0; j < C_RW; ++j) {
    accL[j] = (v2f){0.f, 0.f};
    accH[j] = (v2f){0.f, 0.f};
    int w = chunk * C_RW + j;
    int cls = (w == 0) ? 7 : ((w == 223) ? 8 : (w % 7));
    int base = i * C_NCLS + cls;
    int offA = meta[base * 2 + 0];
    int rl   = meta[base * 2 + 1];
    int start = offA + 128 * (w / 7);     // 4-aligned by construction
    if (start < U0) U0 = start;
    if (start + rl > U1) U1 = start + rl;
  }

  int m0 = U0 + piece * C_M;
  int m1 = m0 + C_M; if (m1 > U1) m1 = U1;
  if (m0 >= m1) return;                  // uniform across block

  int nIt = (m1 - m0 + 7) >> 3;          // 8-m steps (<=64)

  // four phases of <=16 its; phase stages quads [2*it0, 2*it1) (<=32 = 8 KB)
  for (int ph = 0; ph < 4; ++ph) {
    int it0 = ph << 4;
    if (it0 >= nIt) break;
    int it1 = nIt < it0 + 16 ? nIt : it0 + 16;
    int qn  = 2 * (it1 - it0);           // <= 32

    // ---- stage H quads: lanes 0-31 stage even j, lanes 32-63 odd j ----
    // staged float idx within row in [-236, 3866]: front underflow lands in the
    // previous row's >=503-float back guard (or the zeroed pre-Hbuf pad for row
    // 0); forward max stays inside this row's back guard. All zeros or data.
    {
      int ln = lane & 31;
      if (ln < qn) {
#pragma unroll
        for (int jj = 0; jj < C_RW; jj += 2) {
          int j = jj + half;
          int w = chunk * C_RW + j;
          int cls = (w == 0) ? 7 : ((w == 223) ? 8 : (w % 7));
          int base = i * C_NCLS + cls;
          int start = meta[base * 2 + 0] + 128 * (w / 7);
          const float* src = Hbuf + (long long)base * C_HSTRIDE
                           + (C_HGUARD + m0 - start) + 8 * it0;
          Hs[j][ln] = *(const v4f*)(src + 4 * ln);
        }
      }
    }
    __syncthreads();

    // ---- inner loop: half h covers m0+8it+4h..+3; quad index 2(it-it0)+half ----
    // 1-it lookahead prefetch: n* loads issue before the 128-FMA block consuming
    // c*, giving ~512 VALU cycles of latency cover. Overread past m1 is <=15
    // rows, and U1+15 < 8192 = xpQ rows -> always in-bounds, values unused.
    const float* xr = xpQ + ((long long)(m0 + 8 * it0 + 4 * half) << 7) + (g << 2);
    v4f c0 = *(const v4f*)(xr);
    v4f c1 = *(const v4f*)(xr + 128);
    v4f c2 = *(const v4f*)(xr + 256);
    v4f c3 = *(const v4f*)(xr + 384);
    xr += 1024;
#pragma unroll 2
    for (int it = it0; it < it1; ++it) {
      v4f n0 = *(const v4f*)(xr);
      v4f n1 = *(const v4f*)(xr + 128);
      v4f n2 = *(const v4f*)(xr + 256);
      v4f n3 = *(const v4f*)(xr + 384);
      xr += 1024;
      int lq = 2 * (it - it0) + half;
#pragma unroll
      for (int j = 0; j < C_RW; ++j) {
        v4f h = Hs[j][lq];
        accL[j] += c0.xy * h.x; accH[j] += c0.zw * h.x;
        accL[j] += c1.xy * h.y; accH[j] += c1.zw * h.y;
        accL[j] += c2.xy * h.z; accH[j] += c2.zw * h.z;
        accL[j] += c3.xy * h.w; accH[j] += c3.zw * h.w;
      }
      c0 = n0; c1 = n1; c2 = n2; c3 = n3;
    }
    __syncthreads();   // protect Hs before next phase overwrites
  }

  // ---- combine halves, then coalesced fp32 atomics (lanes 0-31, 4 batches of 32) ----
#pragma unroll
  for (int j = 0; j < C_RW; ++j) {
    float s0 = accL[j].x, s1 = accL[j].y, s2 = accH[j].x, s3 = accH[j].y;
    s0 += __shfl_xor(s0, 32);
    s1 += __shfl_xor(s1, 32);
    s2 += __shfl_xor(s2, 32);
    s3 += __shfl_xor(s3, 32);
    if (lane < 32) {
      int w = chunk * C_RW + j;
      float* dst = OT + ((long long)i * C_NW + w) * C_SIGP;
      atomicAdd(dst + g,      s0);     // slots  0..31  contiguous across lanes
      atomicAdd(dst + 32 + g, s1);     // slots 32..63
      atomicAdd(dst + 64 + g, s2);     // slots 64..95
      atomicAdd(dst + 96 + g, s3);     // slots 96..127 (pad)
    }
  }
}

// ---------------- final: scale-dim bilinear upsample 128->224 + layout ----------------
__global__ __launch_bounds__(256) void k_final(const float* __restrict__ OT,
                                               float* __restrict__ out) {
  int wt = blockIdx.x;    // 0..27
  int h  = blockIdx.y;    // 0..223

  float inv = 128.0f / 224.0f;               // f32 like jax
  float sg = ((float)h + 0.5f) * inv - 0.5f;
  float sgf = floorf(sg);
  int s0 = (int)sgf;
  float fr = sg - sgf;
  int r0, r1;
  if (s0 < 0)        { r0 = 0;   r1 = 0;   fr = 0.f; }
  else if (s0 >= 127){ r0 = 127; r1 = 127; fr = 0.f; }
  else               { r0 = s0;  r1 = s0 + 1; }

  __shared__ float sh0[8 * 132];
  __shared__ float sh1[8 * 132];
  for (int q = threadIdx.x; q < 1024; q += 256) {
    int wp  = q >> 7;
    int sg2 = q & 127;
    int wg  = wt * 8 + wp;
    sh0[wp * 132 + sg2] = OT[((long long)r0 * C_NW + wg) * C_SIGP + sg2];
    sh1[wp * 132 + sg2] = OT[((long long)r1 * C_NW + wg) * C_SIGP + sg2];
  }
  __syncthreads();

  int b  = threadIdx.x >> 3;    // 0..31
  int wp = threadIdx.x & 7;     // 0..7
  int obase = ((b * 224 + h) * 224 + wt * 8 + wp) * 3;
#pragma unroll
  for (int c = 0; c < 3; ++c) {
    int sidx = wp * 132 + c * 32 + b;
    float a0 = sh0[sidx];
    float a1 = sh1[sidx];
    out[obase + c] = (1.0f - fr) * a0 + fr * a1;
  }
}

// ---------------- launch ----------------
extern "C" void kernel_launch(void* const* d_in, const int* in_sizes, int n_in,
                              void* d_out, int out_size, void* d_ws, size_t ws_size,
                              hipStream_t stream) {
  const float* x       = (const float*)d_in[0];   // (32,4096,3) f32
  const float* int_psi = (const float*)d_in[1];   // (4096,) f32
  float* out = (float*)d_out;

  // workspace layout: xpQ (4 MB) | pad (2 KB) | Hbuf (18.3 MB) | meta (9 KB) | OT (14.7 MB)
  float* xpQ  = (float*)d_ws;                                   // 8192*128 floats
  float* Hbuf = xpQ + (long long)C_XROWS * C_SIGP + C_HPAD;     // 1152*3968 floats
  int*   meta = (int*)(Hbuf + (long long)128 * C_NCLS * C_HSTRIDE); // 2304 ints
  float* OT   = (float*)(meta + 2304);                          // 128*224*128 floats

  k_build_H<<<dim3(128, 10), dim3(256), 0, stream>>>(int_psi, x, Hbuf, meta, xpQ, OT);
  k_cwt_main<<<dim3(C_NP, C_NCH, 128), dim3(64), 0, stream>>>(xpQ, Hbuf, meta, OT);
  k_final<<<dim3(28, 224), dim3(256), 0, stream>>>(OT, out);
}

// Round 2
// 194.711 us; speedup vs baseline: 2.1171x; 2.1171x over previous
//
#include <hip/hip_runtime.h>
#include <cmath>
#include <cstdint>

// ---------------- static configuration ----------------
// B=32, T=4096, C=3, 128 scales, out 224x224, N_PSI=4096, pad=2047.
// slot = c*32 + b (96 real, padded to 128), padded signal length 8190.
// Composite kernel per (scale, class): class 0..6 = interior phase (w mod 7),
// class 7 = w==0 (left-clipped), class 8 = w==223 (right-clipped).
// H rows: [160 zero guard][<=3314 data, 4-aligned][>=300 zero guard], stride 3776.
//
// x layout: SLOT-INTERLEAVED xpQ[m][g*4+e] = xp[m][g + 32*e], g in [0,32), e in [0,4).
// Lane g loads one v4f = slots {g, g+32, g+64, g+96} at time m (2 packed pairs),
// and per-e combined outputs across lanes 0-31 are 32 contiguous OT words ->
// coalesced atomic batches.
//
// Round 13: r12 (RW=16 + prefetch) SPILLED (VGPR_Count=64 < 64 acc floats needed
// -> accumulators in scratch; occupancy 33->10%, dur 113->351us). Revert to the
// verified r11 structure (RW=8, 52 VGPR, no spill) and apply ONLY the prefetch
// lever: explicit 1-iteration lookahead of the 4 xpQ quads. 32 acc + 16 cur +
// 16 next + temps ~= 90 VGPR < 128 cap -> no spill; each 4-load batch gets
// >=128 VALU-cycles (256-512 with unroll-2) of latency cover vs the ~400-600cy
// L2/L3-class xpQ latency that capped per-wave duty at ~20% in r11.

constexpr int C_TP     = 8190;
constexpr int C_XROWS  = 8192;   // time rows in xpQ
constexpr long long C_HSTRIDE = 3776;
constexpr int C_HGUARD = 160;
constexpr int C_NCLS   = 9;
constexpr int C_RW     = 8;      // w's per block (consecutive)
constexpr int C_NCH    = 28;     // 224 / C_RW
constexpr int C_NW     = 224;
constexpr int C_SIGP   = 128;    // padded slots
constexpr int C_M      = 512;    // m per piece
constexpr int C_NP     = 7;      // max pieces
constexpr int C_SQ     = 64;     // staged quads per row per phase (8 KB total)

typedef float v2f __attribute__((ext_vector_type(2)));
typedef float v4f __attribute__((ext_vector_type(4)));

// Replicate numpy: scales = logspace(log10(2), log10(204), 128).astype(f32);
// K = ceil(16*s + 1); d = (4094-K)//2; a = s * (16/4095) in double.
__device__ __forceinline__ void scale_params(int i, float& s32, int& K, int& d, double& a) {
  const double l2   = log10(2.0);
  const double l204 = log10(204.0);
  double step = (l204 - l2) / 127.0;
  double e = (i == 127) ? l204 : ((double)i * step + l2);
  double sv = pow(10.0, e);
  s32 = (float)sv;
  double sp = (double)s32;
  K = (int)ceil(sp * 16.0 + 1.0);
  d = (4094 - K) >> 1;
  a = sp * (16.0 / 4095.0);
}

// ---------------- build composite kernels H (+fused OT zero & xpQ build) -------------
// grid (128, 10): cls<9 -> H row; cls==9 -> zero OT strip + build xpQ strip.
__global__ __launch_bounds__(256) void k_build_H(const float* __restrict__ int_psi,
                                                 const float* __restrict__ x,
                                                 float* __restrict__ Hbuf,
                                                 int* __restrict__ meta,
                                                 float* __restrict__ xpQ,
                                                 float* __restrict__ OT) {
  int i   = blockIdx.x;   // scale (or strip index for cls==9)
  int cls = blockIdx.y;   // class

  if (cls == 9) {
    // zero OT strip: 128 strips x 7168 float4
    float4* otz = (float4*)OT + (long long)i * 7168;
    float4 z4 = make_float4(0.f, 0.f, 0.f, 0.f);
    for (int q = threadIdx.x; q < 7168; q += 256) otz[q] = z4;
    // build xpQ strip: 128 strips x 8192 floats; slot-interleaved, reflect pad
    for (int q = threadIdx.x; q < 8192; q += 256) {
      int idx = i * 8192 + q;
      int r   = idx & 127;
      int p   = idx >> 7;
      int g   = r >> 2;       // b
      int e   = r & 3;        // c (e==3 -> pad)
      float val = 0.f;
      if (e < 3 && p < C_TP) {
        int t = p - 2047;
        if (t < 0) t = -t;                 // x[2047-p]
        else if (t > 4095) t = 8190 - t;   // x[10237-p]
        val = x[(g * 4096 + t) * 3 + e];
      }
      xpQ[idx] = val;
    }
    return;
  }

  float s32; int K, d; double a;
  scale_params(i, s32, K, d, a);

  int wr = (cls < 7) ? ((cls == 0) ? 7 : cls) : ((cls == 7) ? 0 : 223);
  double ks = 4096.0 / 224.0;
  double sf = ((double)wr + 0.5) * ks - 0.5;
  int t_lo = (int)floor(sf - ks) + 1;
  int t_hi = (int)ceil(sf + ks) - 1;
  if (t_lo < 0) t_lo = 0;
  if (t_hi > 4095) t_hi = 4095;
  int nt  = t_hi - t_lo + 1;   // <= 37
  int npv = nt + 1;            // conv-point weights

  int p_lo = t_lo + d;
  int Lh   = K + npv - 1;
  int kr   = (cls == 0) ? 1 : ((cls == 8) ? 31 : 0);
  int off0 = p_lo - 128 * kr;
  int shift = off0 & 3;
  int offA  = off0 - shift;
  int rowLen = (shift + Lh + 3) & ~3;

  __shared__ double Wt_sh[40];
  __shared__ float  v_shf[40];
  __shared__ float  kern_sh[3352];

  // zero only the guard regions (data region [g0,g1) fully overwritten below)
  float* rowFull = Hbuf + (long long)(i * C_NCLS + cls) * C_HSTRIDE;
  int g0 = C_HGUARD + shift;
  int g1 = g0 + Lh;
  for (int q = threadIdx.x; q < g0; q += 256) rowFull[q] = 0.f;
  for (int q = g1 + threadIdx.x; q < (int)C_HSTRIDE; q += 256) rowFull[q] = 0.f;

  if (threadIdx.x == 0) {
    double Z = 0.0;
    for (int t = 0; t < nt; ++t) {
      double wv = 1.0 - fabs(sf - (double)(t + t_lo)) / ks;
      if (wv < 0.0) wv = 0.0;
      Wt_sh[t] = wv; Z += wv;
    }
    for (int t = 0; t < nt; ++t) Wt_sh[t] = Wt_sh[t] / Z;
    double sq = sqrt((double)s32);
    // v[p_lo + q] = -sqrt(s) * (Wt[q-1] - Wt[q])   (built in double, used f32)
    for (int q = 0; q < 40; ++q) {
      double wm1 = (q >= 1 && q <= nt)  ? Wt_sh[q - 1] : 0.0;
      double w0  = (q < nt)             ? Wt_sh[q]     : 0.0;
      v_shf[q] = (float)(-sq * (wm1 - w0));
    }
  }

  // flipped gathered wavelet: kernW[tau] = int_psi[clip(floor((K-1-tau)/a))]
  float* kernp = kern_sh + 40;
  int fillN = K + 80;
  for (int q = threadIdx.x; q < fillN; q += 256) {
    int tau = q - 40;
    float kv = 0.f;
    if (tau >= 0 && tau < K) {
      int u = K - 1 - tau;
      int jj = (int)floor((double)u / a);
      jj = jj < 0 ? 0 : (jj > 4095 ? 4095 : jj);
      kv = int_psi[jj];
    }
    kern_sh[q] = kv;
  }
  __syncthreads();

  float* row = rowFull + C_HGUARD;
  for (int q = threadIdx.x; q < Lh; q += 256) {
    float acc = 0.f;
    for (int t = 0; t < npv; ++t) acc += v_shf[t] * kernp[q - t];
    row[shift + q] = acc;
  }
  if (threadIdx.x == 0) {
    meta[(i * C_NCLS + cls) * 2 + 0] = offA;
    meta[(i * C_NCLS + cls) * 2 + 1] = rowLen;
  }
}

// ---------------- main: OT[scale][w][slot] += sum_{m in piece} xp[m][slot]*H_w[m] ------
// grid (piece, chunk, scale'), scale' reversed so heavy scales dispatch first.
// ONE wave; iteration-granular half-wave m-split; lane owns slots {g,g+32,g+64,g+96}.
// r13: + explicit 1-it lookahead prefetch of the 4 xpQ quads.
__global__ __launch_bounds__(64, 4) void k_cwt_main(const float* __restrict__ xpQ,
                                                    const float* __restrict__ Hbuf,
                                                    const int* __restrict__ meta,
                                                    float* __restrict__ OT) {
  int piece = blockIdx.x;           // 0..6
  int chunk = blockIdx.y;           // 0..27
  int i     = 127 - blockIdx.z;     // heavy scales first
  int lane  = threadIdx.x;          // 0..63
  int g     = lane & 31;
  int half  = lane >> 5;

  __shared__ v4f Hs[C_RW][C_SQ];    // 8 KB (per phase)

  v2f accL[C_RW], accH[C_RW];
  const float* rowP[C_RW];
  int startj[C_RW];
  int U0 = 0x7fffffff, U1 = 0;
#pragma unroll
  for (int j = 0; j < C_RW; ++j) {
    accL[j] = (v2f){0.f, 0.f};
    accH[j] = (v2f){0.f, 0.f};
    int w = chunk * C_RW + j;
    int cls = (w == 0) ? 7 : ((w == 223) ? 8 : (w % 7));
    int k = w / 7;
    int base = i * C_NCLS + cls;
    int offA = meta[base * 2 + 0];
    int rl   = meta[base * 2 + 1];
    int start = offA + 128 * k;           // 4-aligned by construction
    startj[j] = start;
    if (start < U0) U0 = start;
    if (start + rl > U1) U1 = start + rl;
    rowP[j] = Hbuf + (long long)base * C_HSTRIDE;
  }

  int m0 = U0 + piece * C_M;
  int m1 = m0 + C_M; if (m1 > U1) m1 = U1;
  if (m0 >= m1) return;                  // uniform across block

  int len = m1 - m0;
  int nIt = (len + 7) >> 3;              // 8-m steps (<=64)

  // two phases of <=32 steps; phase stages quads [2*it0, 2*it1) (<=64 = 8 KB)
  for (int ph = 0; ph < 2; ++ph) {
    int it0 = ph << 5;
    if (it0 >= nIt) break;
    int it1 = nIt < it0 + 32 ? nIt : it0 + 32;
    int qn  = 2 * (it1 - it0);

    // ---- stage H quads for this phase ----
    // staged float idx within row <= HGUARD + (m1+7-startj) <= 3617 < 3776:
    // always row data or zero guard. relS >= 160-136 > 0.
#pragma unroll
    for (int j = 0; j < C_RW; ++j) {
      const float* src = rowP[j] + (C_HGUARD + m0 - startj[j]) + 8 * it0;
      if (lane < qn) Hs[j][lane] = *(const v4f*)(src + 4 * lane);
    }
    __syncthreads();

    // ---- inner loop: half h covers m0+8it+4h..+3; quad index 2(it-it0)+half ----
    // 1-it lookahead: n* loads issue before the 64-FMA block consuming c*,
    // giving >=128 VALU cycles (256-512 with unroll 2) of latency cover.
    // Overread past m1 is <=23 rows; U1+23 < 7820 < 8192 xpQ rows -> in-bounds,
    // values unused.
    const float* xr = xpQ + ((long long)(m0 + 8 * it0 + 4 * half) << 7) + (g << 2);
    v4f c0 = *(const v4f*)(xr);
    v4f c1 = *(const v4f*)(xr + 128);
    v4f c2 = *(const v4f*)(xr + 256);
    v4f c3 = *(const v4f*)(xr + 384);
    xr += 1024;
#pragma unroll 2
    for (int it = it0; it < it1; ++it) {
      v4f n0 = *(const v4f*)(xr);
      v4f n1 = *(const v4f*)(xr + 128);
      v4f n2 = *(const v4f*)(xr + 256);
      v4f n3 = *(const v4f*)(xr + 384);
      xr += 1024;
      int lq = 2 * (it - it0) + half;
#pragma unroll
      for (int j = 0; j < C_RW; ++j) {
        v4f h = Hs[j][lq];
        accL[j] += c0.xy * h.x; accH[j] += c0.zw * h.x;
        accL[j] += c1.xy * h.y; accH[j] += c1.zw * h.y;
        accL[j] += c2.xy * h.z; accH[j] += c2.zw * h.z;
        accL[j] += c3.xy * h.w; accH[j] += c3.zw * h.w;
      }
      c0 = n0; c1 = n1; c2 = n2; c3 = n3;
    }
    __syncthreads();   // protect Hs before next phase overwrites
  }

  // ---- combine halves, then coalesced fp32 atomics (lanes 0-31, 4 batches of 32) ----
#pragma unroll
  for (int j = 0; j < C_RW; ++j) {
    float s0 = accL[j].x, s1 = accL[j].y, s2 = accH[j].x, s3 = accH[j].y;
    s0 += __shfl_xor(s0, 32);
    s1 += __shfl_xor(s1, 32);
    s2 += __shfl_xor(s2, 32);
    s3 += __shfl_xor(s3, 32);
    if (lane < 32) {
      int w = chunk * C_RW + j;
      float* dst = OT + ((long long)i * C_NW + w) * C_SIGP;
      atomicAdd(dst + g,      s0);     // slots  0..31  contiguous across lanes
      atomicAdd(dst + 32 + g, s1);     // slots 32..63
      atomicAdd(dst + 64 + g, s2);     // slots 64..95
      atomicAdd(dst + 96 + g, s3);     // slots 96..127 (pad)
    }
  }
}

// ---------------- final: scale-dim bilinear upsample 128->224 + layout ----------------
__global__ __launch_bounds__(256) void k_final(const float* __restrict__ OT,
                                               float* __restrict__ out) {
  int wt = blockIdx.x;    // 0..27
  int h  = blockIdx.y;    // 0..223

  float inv = 128.0f / 224.0f;               // f32 like jax
  float sg = ((float)h + 0.5f) * inv - 0.5f;
  float sgf = floorf(sg);
  int s0 = (int)sgf;
  float fr = sg - sgf;
  int r0, r1;
  if (s0 < 0)        { r0 = 0;   r1 = 0;   fr = 0.f; }
  else if (s0 >= 127){ r0 = 127; r1 = 127; fr = 0.f; }
  else               { r0 = s0;  r1 = s0 + 1; }

  __shared__ float sh0[8 * 132];
  __shared__ float sh1[8 * 132];
  for (int q = threadIdx.x; q < 1024; q += 256) {
    int wp  = q >> 7;
    int sg2 = q & 127;
    int wg  = wt * 8 + wp;
    sh0[wp * 132 + sg2] = OT[((long long)r0 * C_NW + wg) * C_SIGP + sg2];
    sh1[wp * 132 + sg2] = OT[((long long)r1 * C_NW + wg) * C_SIGP + sg2];
  }
  __syncthreads();

  int b  = threadIdx.x >> 3;    // 0..31
  int wp = threadIdx.x & 7;     // 0..7
  int obase = ((b * 224 + h) * 224 + wt * 8 + wp) * 3;
#pragma unroll
  for (int c = 0; c < 3; ++c) {
    int sidx = wp * 132 + c * 32 + b;
    float a0 = sh0[sidx];
    float a1 = sh1[sidx];
    out[obase + c] = (1.0f - fr) * a0 + fr * a1;
  }
}

// ---------------- launch ----------------
extern "C" void kernel_launch(void* const* d_in, const int* in_sizes, int n_in,
                              void* d_out, int out_size, void* d_ws, size_t ws_size,
                              hipStream_t stream) {
  const float* x       = (const float*)d_in[0];   // (32,4096,3) f32
  const float* int_psi = (const float*)d_in[1];   // (4096,) f32
  float* out = (float*)d_out;

  // workspace layout: xpQ (4 MB) | Hbuf (17.4 MB) | meta (9 KB) | OT (14.7 MB)
  float* xpQ  = (float*)d_ws;                                   // 8192*128 floats
  float* Hbuf = xpQ + (long long)C_XROWS * C_SIGP;              // 1152*3776 floats
  int*   meta = (int*)(Hbuf + (long long)128 * C_NCLS * C_HSTRIDE); // 2304 ints
  float* OT   = (float*)(meta + 2304);                          // 128*224*128 floats

  k_build_H<<<dim3(128, 10), dim3(256), 0, stream>>>(int_psi, x, Hbuf, meta, xpQ, OT);
  k_cwt_main<<<dim3(C_NP, C_NCH, 128), dim3(64), 0, stream>>>(xpQ, Hbuf, meta, OT);
  k_final<<<dim3(28, 224), dim3(256), 0, stream>>>(OT, out);
}